// Round 3
// baseline (762.533 us; speedup 1.0000x reference)
//
#include <hip/hip_runtime.h>

// ---------------------------------------------------------------------------
// SharedPPOSoftModularizedMLP on MI355X (gfx950)
// B=8192, OBS=128, TASK=64, D=1024, E=8, L=4
// bf16 MFMA (16x16x32), fp32 accumulate.
// R11: expert GEMMs -> gemm_p128: 128x128 tile, 4 waves, 4-slot sub-K=32 LDS
//      ring (64KB -> 2 blocks/CU), counted vmcnt(4), REGISTER double-buffered
//      fragments (next phase's 8 ds_read_b128 issue under current 16-MFMA
//      cluster).  Kills the lockstep post-barrier LDS-latency stall that
//      capped the 256^2 version at MfmaUtil 36%.  Tail (mix_head etc.)
//      unchanged from R10.
// ---------------------------------------------------------------------------

typedef __attribute__((ext_vector_type(8))) short short8;   // 8 x bf16 frag
typedef __attribute__((ext_vector_type(4))) float floatx4;  // MFMA acc
typedef unsigned short us;

__device__ __forceinline__ us f2bf(float f) {
  union { float f; unsigned u; } v; v.f = f;
  return (us)((v.u + 0x7FFFu + ((v.u >> 16) & 1u)) >> 16);  // RNE
}
__device__ __forceinline__ float bf2f(us h) {
  union { unsigned u; float f; } v; v.u = ((unsigned)h) << 16;
  return v.f;
}

// async global->LDS, 16B per lane; lds dest = wave-uniform base + lane*16
__device__ __forceinline__ void g2lds16(const void* g, void* l) {
  __builtin_amdgcn_global_load_lds(
      (const __attribute__((address_space(1))) void*)g,
      (__attribute__((address_space(3))) void*)l, 16, 0, 0);
}

// ---------------------------------------------------------------------------
// Main-path GEMM: C[M,N] = post(act(A@Bt^T + bias)); all bf16, M,N %128==0.
// post: MUL -> elementwise * Mul[M,N]; RELU2 -> relu after MUL.
// CB2: Cb = value, Cb2 = relu(value).
// grid=(N/128, M/128, E). XCD chunk swizzle when total blocks % 8 == 0.
// ---------------------------------------------------------------------------
template<bool BIAS, bool RELU, bool MUL, bool RELU2, bool CB2>
__global__ __launch_bounds__(256)
void gemm_main(const us* __restrict__ A, const us* __restrict__ Bt,
               const float* __restrict__ bias,
               us* __restrict__ Cb, us* __restrict__ Cb2,
               const us* __restrict__ Mul,
               int N, int K, int lda, int ldb,
               long long sA, long long sB, long long sBias, long long sC)
{
  // ---- XCD chunk swizzle ----
  int bx = blockIdx.x, by = blockIdx.y, bz = blockIdx.z;
  {
    const int gx = gridDim.x, gy = gridDim.y;
    const int total = gx * gy * gridDim.z;
    if ((total & 7) == 0) {
      int L = bx + gx * (by + gy * bz);
      int per = total >> 3;
      int w = (L & 7) * per + (L >> 3);
      bx = w % gx; w /= gx;
      by = w % gy; bz = w / gy;
    }
  }

  const int e = bz;
  const us* Ab = A + (size_t)e * sA;
  const us* Bb = Bt + (size_t)e * sB;

  const int m0 = by * 128;
  const int n0 = bx * 128;
  const int tid = threadIdx.x;
  const int wave = tid >> 6;
  const int lane = tid & 63;
  const int wm = (wave >> 1) * 64;
  const int wn = (wave & 1) * 64;
  const int lr = lane & 15;
  const int lq = lane >> 4;

  // staging: A = smem[0..8191], B = smem[8192..16383]  (us units)
  // epilogue tile: smem[0..17407] as [128][136] us  (R4 layout)
  __shared__ __align__(16) us smem[128 * 136 + 64];
  us* ldsA = smem;
  us* ldsB = smem + 128 * 64;

  floatx4 acc[4][4];
#pragma unroll
  for (int i = 0; i < 4; ++i)
#pragma unroll
    for (int j = 0; j < 4; ++j) acc[i][j] = (floatx4){0.f, 0.f, 0.f, 0.f};

  for (int k0 = 0; k0 < K; k0 += 64) {
#pragma unroll
    for (int c = 0; c < 4; ++c) {
      int slot = c * 256 + tid;               // physical 16B chunk
      int r = slot >> 3;
      int s = (slot & 7) ^ (r & 7);           // logical slab (XOR swizzle)
      int ubase = (c * 256 + wave * 64) * 8;  // wave-uniform LDS base (us)
      g2lds16(Ab + (size_t)(m0 + r) * lda + k0 + s * 8, ldsA + ubase);
      g2lds16(Bb + (size_t)(n0 + r) * ldb + k0 + s * 8, ldsB + ubase);
    }
    __syncthreads();

#pragma unroll
    for (int kk = 0; kk < 2; ++kk) {
      short8 af[4], bfr[4];
#pragma unroll
      for (int t = 0; t < 4; ++t) {
        int m = wm + t * 16 + lr;
        int s = kk * 4 + lq;
        af[t]  = *(const short8*)(ldsA + (size_t)(m * 8 + (s ^ (m & 7))) * 8);
        int n = wn + t * 16 + lr;
        bfr[t] = *(const short8*)(ldsB + (size_t)(n * 8 + (s ^ (n & 7))) * 8);
      }
#pragma unroll
      for (int mt = 0; mt < 4; ++mt)
#pragma unroll
        for (int nt = 0; nt < 4; ++nt)
          acc[mt][nt] = __builtin_amdgcn_mfma_f32_16x16x32_bf16(
              af[mt], bfr[nt], acc[mt][nt], 0, 0, 0);
    }
    __syncthreads();
  }

  // ---- epilogue (R4): stage bf16 tile in LDS [128][136], store dwordx4 ----
  // C/D layout: col = lane&15, row = lq*4 + r
#pragma unroll
  for (int nt = 0; nt < 4; ++nt) {
    int coll = wn + nt * 16 + lr;
    int col = n0 + coll;
    float bv = BIAS ? bias[(size_t)e * sBias + col] : 0.f;
#pragma unroll
    for (int mt = 0; mt < 4; ++mt) {
      int rowb = wm + mt * 16 + lq * 4;
#pragma unroll
      for (int r = 0; r < 4; ++r) {
        int rowl = rowb + r;
        float v = acc[mt][nt][r] + bv;
        if (RELU) v = fmaxf(v, 0.f);
        if (MUL) v *= bf2f(Mul[(size_t)(m0 + rowl) * N + col]);
        if (RELU2) v = fmaxf(v, 0.f);
        smem[rowl * 136 + coll] = f2bf(v);
      }
    }
  }
  __syncthreads();
#pragma unroll
  for (int c = 0; c < 8; ++c) {
    int sl = c * 256 + tid;
    int rowl = sl >> 4;
    int seg = sl & 15;
    short8 val = *(const short8*)(smem + rowl * 136 + seg * 8);
    size_t gidx = (size_t)e * sC + (size_t)(m0 + rowl) * N + n0 + seg * 8;
    *(short8*)(Cb + gidx) = val;
    if (CB2) {
      short8 rl;
#pragma unroll
      for (int q = 0; q < 8; ++q) {
        us u = (us)val[q];
        rl[q] = (short)((u & 0x8000u) ? (us)0 : u);
      }
      *(short8*)(Cb2 + gidx) = rl;
    }
  }
}

// ---------------------------------------------------------------------------
// gemm_p128: deep-pipelined 128x128-tile GEMM, 2 blocks/CU.
//   C[M,N] = relu?(A@Bt^T + bias), bf16 in/out, fp32 acc.
//   Requirements: M%128==0, N%128==0, K%64==0, K>=128.
//   grid = (N/128, M/128, E), block = 256 (4 waves, 2M x 2N; 64x64/wave).
// Schedule: sub-K=32 phases on a 4-slot LDS ring (64KB total -> TWO blocks
// co-resident per CU cover each other's barriers/epilogues).  Fragments are
// REGISTER double-buffered: phase q computes set[q&1] (already in regs) while
// issuing the 8 ds_read_b128 for phase q+1 into set[~q&1] -- the LDS latency
// hides under the 16-MFMA cluster, so post-barrier MFMA issues immediately.
// Per phase: vmcnt(4) [stage q+1 landed own-wave] + barrier [all waves] ->
// stage(q+3) -> prefetch frags(q+1) -> 16 MFMA.  Slot (q+3)&3 = (q-1)&3 was
// last read at phase q-2 (prefetch for q-1), fenced by >=1 barrier.
// ---------------------------------------------------------------------------
template<bool BIAS, bool RELU>
__global__ __launch_bounds__(256, 2)
void gemm_p128(const us* __restrict__ A, const us* __restrict__ Bt,
               const float* __restrict__ bias, us* __restrict__ Cb,
               int N, int K, int lda, int ldb,
               long long sA, long long sB, long long sBias, long long sC)
{
  // ---- XCD chunk swizzle ----
  int bx = blockIdx.x, by = blockIdx.y, bz = blockIdx.z;
  {
    const int gx = gridDim.x, gy = gridDim.y;
    const int total = gx * gy * gridDim.z;
    if ((total & 7) == 0) {
      int L = bx + gx * (by + gy * bz);
      int per = total >> 3;
      int w = (L & 7) * per + (L >> 3);
      bx = w % gx; w /= gx;
      by = w % gy; bz = w / gy;
    }
  }
  const int e = bz;
  const us* Ab = A + (size_t)e * sA;
  const us* Bb = Bt + (size_t)e * sB;

  const int m0 = by * 128;
  const int n0 = bx * 128;
  const int tid  = threadIdx.x;
  const int wave = tid >> 6;
  const int lane = tid & 63;
  const int wr = (wave >> 1) * 64;    // 2 M-waves x 64 rows
  const int wc = (wave & 1) * 64;     // 2 N-waves x 64 cols
  const int lr = lane & 15;
  const int lq = lane >> 4;

  // LDS ring: A slots [0..16383], B slots [16384..32767] (us units).
  // Slot = 128 rows x 32 k bf16 = 4096 us (8KB).  Element (row, slab)
  // [slab = 16B unit of 8 bf16, 0..3] lives in 128B line L = row>>1 at
  // position p = (slab | ((row&1)<<2)) ^ (L&7)  (proven layout from R9/R10,
  // measured 0 bank conflicts).  Epilogue reuses smem as [128][136] us.
  __shared__ __align__(16) us smem[32768];

  floatx4 acc[4][4];
#pragma unroll
  for (int i = 0; i < 4; ++i)
#pragma unroll
    for (int j = 0; j < 4; ++j) acc[i][j] = (floatx4){0.f, 0.f, 0.f, 0.f};

  // ---- per-thread staging constants (2 A-loads + 2 B-loads per sub) ----
  const us *srcA0, *srcA1, *srcB0, *srcB1;
  {
    int c = tid;                    // physical 16B chunk 0..255
    int Ln = c >> 3, pos = c & 7, q = pos ^ (Ln & 7);
    int row = 2 * Ln + (q >> 2), so = (q & 3) * 8;
    srcA0 = Ab + (size_t)(m0 + row) * lda + so;
    srcB0 = Bb + (size_t)(n0 + row) * ldb + so;
    c = tid + 256;                  // chunk 256..511
    Ln = c >> 3; pos = c & 7; q = pos ^ (Ln & 7);
    row = 2 * Ln + (q >> 2); so = (q & 3) * 8;
    srcA1 = Ab + (size_t)(m0 + row) * lda + so;
    srcB1 = Bb + (size_t)(n0 + row) * ldb + so;
  }
  const int dst0 = wave * 512;      // wave-uniform LDS chunk base (us)

  // ---- per-lane fragment read offsets (constant across phases) ----
  int offA[4], offB[4];
#pragma unroll
  for (int t = 0; t < 4; ++t) {
    int m  = wr + t * 16 + lr;
    int Ln = m >> 1;
    offA[t] = Ln * 64 + (((lq | ((m & 1) << 2)) ^ (Ln & 7)) << 3);
    int n  = wc + t * 16 + lr;
    Ln = n >> 1;
    offB[t] = Ln * 64 + (((lq | ((n & 1) << 2)) ^ (Ln & 7)) << 3);
  }

  auto stage = [&](int s) {
    us* a = smem + (s & 3) * 4096;
    us* b = smem + 16384 + (s & 3) * 4096;
    const int ko = s << 5;          // global k offset (elements)
    g2lds16(srcA0 + ko, a + dst0);
    g2lds16(srcA1 + ko, a + dst0 + 2048);
    g2lds16(srcB0 + ko, b + dst0);
    g2lds16(srcB1 + ko, b + dst0 + 2048);
  };

  auto loadfrag = [&](short8 (&af)[4], short8 (&bf)[4], int slot) {
    const us* a = smem + slot * 4096;
    const us* b = smem + 16384 + slot * 4096;
#pragma unroll
    for (int t = 0; t < 4; ++t) bf[t] = *(const short8*)(b + offB[t]);
#pragma unroll
    for (int t = 0; t < 4; ++t) af[t] = *(const short8*)(a + offA[t]);
  };

  auto mfma16 = [&](short8 (&af)[4], short8 (&bf)[4]) {
    __builtin_amdgcn_s_setprio(1);
#pragma unroll
    for (int mt = 0; mt < 4; ++mt)
#pragma unroll
      for (int nt = 0; nt < 4; ++nt)
        acc[mt][nt] = __builtin_amdgcn_mfma_f32_16x16x32_bf16(
            af[mt], bf[nt], acc[mt][nt], 0, 0, 0);
    __builtin_amdgcn_s_setprio(0);
  };

  short8 afA[4], bfA[4], afB[4], bfB[4];

  // ---- prologue: 3 sub-tiles in flight, frags for phase 0 in regs ----
  stage(0); stage(1); stage(2);
  asm volatile("s_waitcnt vmcnt(8)" ::: "memory");   // stage 0 landed
  __builtin_amdgcn_s_barrier();
  __builtin_amdgcn_sched_barrier(0);
  loadfrag(afA, bfA, 0);

  const int NP = K >> 5;            // phases (even, >=4 by contract)
  for (int q = 0; q < NP; q += 2) {
    // ---- even phase q: compute set A, prefetch set B for q+1 ----
    if (q <= NP - 3) asm volatile("s_waitcnt vmcnt(4)" ::: "memory");
    else             asm volatile("s_waitcnt vmcnt(0)" ::: "memory");
    __builtin_amdgcn_s_barrier();
    __builtin_amdgcn_sched_barrier(0);
    if (q + 3 <= NP - 1) stage(q + 3);
    if (q <= NP - 2) loadfrag(afB, bfB, (q + 1) & 3);
    mfma16(afA, bfA);
    // ---- odd phase q+1: compute set B, prefetch set A for q+2 ----
    const int q1 = q + 1;
    if (q1 <= NP - 3) asm volatile("s_waitcnt vmcnt(4)" ::: "memory");
    else              asm volatile("s_waitcnt vmcnt(0)" ::: "memory");
    __builtin_amdgcn_s_barrier();
    __builtin_amdgcn_sched_barrier(0);
    if (q1 + 3 <= NP - 1) stage(q1 + 3);
    if (q1 <= NP - 2) loadfrag(afA, bfA, (q1 + 1) & 3);
    mfma16(afB, bfB);
  }

  // ---- epilogue: bias+relu, bf16 via LDS [128][136], 16B stores ----
  __syncthreads();
#pragma unroll
  for (int nt = 0; nt < 4; ++nt) {
    int coll = wc + nt * 16 + lr;
    float bv = BIAS ? bias[(size_t)e * sBias + n0 + coll] : 0.f;
#pragma unroll
    for (int mt = 0; mt < 4; ++mt) {
      int rowb = wr + mt * 16 + lq * 4;
#pragma unroll
      for (int r = 0; r < 4; ++r) {
        float v = acc[mt][nt][r] + bv;
        if (RELU) v = fmaxf(v, 0.f);
        smem[(rowb + r) * 136 + coll] = f2bf(v);
      }
    }
  }
  __syncthreads();
#pragma unroll
  for (int c = 0; c < 8; ++c) {
    int sl = c * 256 + tid;
    int rowl = sl >> 4;
    int seg = sl & 15;
    short8 val = *(const short8*)(smem + rowl * 136 + seg * 8);
    *(short8*)(Cb + (size_t)e * sC + (size_t)(m0 + rowl) * N + n0 + seg * 8) = val;
  }
}

// ---------------------------------------------------------------------------
// Split-K GEMM: atomicAdd fp32 partials.  blockIdx.z = k-chunk (offset by
// sA/sB).  N may be < 128 (B-row clamp).  Used for routing p0/p1 (N=64).
// ---------------------------------------------------------------------------
__global__ __launch_bounds__(256)
void gemm_splitk(const us* __restrict__ A, const us* __restrict__ Bt,
                 float* __restrict__ Cf,
                 int N, int K, int lda, int ldb,
                 long long sA, long long sB,
                 int headout, int rowoff, int Btot)
{
  int bx = blockIdx.x, by = blockIdx.y, bz = blockIdx.z;
  {
    const int gx = gridDim.x, gy = gridDim.y;
    const int total = gx * gy * gridDim.z;
    if ((total & 7) == 0) {
      int L = bx + gx * (by + gy * bz);
      int per = total >> 3;
      int w = (L & 7) * per + (L >> 3);
      bx = w % gx; w /= gx;
      by = w % gy; bz = w / gy;
    }
  }

  const us* Ab = A + (size_t)bz * sA;
  const us* Bb = Bt + (size_t)bz * sB;

  const int m0 = by * 128;
  const int n0 = bx * 128;
  const int tid = threadIdx.x;
  const int wave = tid >> 6;
  const int lane = tid & 63;
  const int wm = (wave >> 1) * 64;
  const int wn = (wave & 1) * 64;
  const int lr = lane & 15;
  const int lq = lane >> 4;

  __shared__ __align__(16) us smem[128 * 128];
  us* ldsA = smem;
  us* ldsB = smem + 128 * 64;

  floatx4 acc[4][4];
#pragma unroll
  for (int i = 0; i < 4; ++i)
#pragma unroll
    for (int j = 0; j < 4; ++j) acc[i][j] = (floatx4){0.f, 0.f, 0.f, 0.f};

  for (int k0 = 0; k0 < K; k0 += 64) {
#pragma unroll
    for (int c = 0; c < 4; ++c) {
      int slot = c * 256 + tid;
      int r = slot >> 3;
      int s = (slot & 7) ^ (r & 7);
      int ubase = (c * 256 + wave * 64) * 8;
      g2lds16(Ab + (size_t)(m0 + r) * lda + k0 + s * 8, ldsA + ubase);
      int nrow = n0 + r; if (nrow > N - 1) nrow = N - 1;  // clamp (N<128)
      g2lds16(Bb + (size_t)nrow * ldb + k0 + s * 8, ldsB + ubase);
    }
    __syncthreads();

#pragma unroll
    for (int kk = 0; kk < 2; ++kk) {
      short8 af[4], bfr[4];
#pragma unroll
      for (int t = 0; t < 4; ++t) {
        int m = wm + t * 16 + lr;
        int s = kk * 4 + lq;
        af[t]  = *(const short8*)(ldsA + (size_t)(m * 8 + (s ^ (m & 7))) * 8);
        int n = wn + t * 16 + lr;
        bfr[t] = *(const short8*)(ldsB + (size_t)(n * 8 + (s ^ (n & 7))) * 8);
      }
#pragma unroll
      for (int mt = 0; mt < 4; ++mt)
#pragma unroll
        for (int nt = 0; nt < 4; ++nt)
          acc[mt][nt] = __builtin_amdgcn_mfma_f32_16x16x32_bf16(
              af[mt], bfr[nt], acc[mt][nt], 0, 0, 0);
    }
    __syncthreads();
  }

#pragma unroll
  for (int nt = 0; nt < 4; ++nt) {
    int col = n0 + wn + nt * 16 + lr;
    if (col >= N) continue;
#pragma unroll
    for (int mt = 0; mt < 4; ++mt) {
      int row = m0 + wm + mt * 16 + lq * 4;
#pragma unroll
      for (int r = 0; r < 4; ++r) {
        float v = acc[mt][nt][r];
        if (headout) {
          size_t di = (col < 8) ? ((size_t)(rowoff + row + r) * 8 + col)
                                : ((size_t)Btot * 8 + rowoff + row + r);
          atomicAdd(Cf + di, v);
        } else {
          atomicAdd(Cf + (size_t)(row + r) * N + col, v);
        }
      }
    }
  }
}

// ---------------------------------------------------------------------------
// Fused prep: all weight transposes (fp32 [R,C] -> bf16 [C,R]), Wh build,
// pbuf zero, out bias init, x split/convert.  One launch, range ladder.
// ---------------------------------------------------------------------------
__device__ __forceinline__ void transpose_tile(
    const float* __restrict__ in, us* __restrict__ out,
    int R, int C, int bx, int by, float (*tile)[33])
{
  const int tx = threadIdx.x & 31, ty = threadIdx.x >> 5;
  const int c0 = bx * 32, r0 = by * 32;
#pragma unroll
  for (int i = 0; i < 4; ++i) {
    int r = r0 + ty + i * 8, c = c0 + tx;
    tile[ty + i * 8][tx] = (r < R && c < C) ? in[(size_t)r * C + c] : 0.f;
  }
  __syncthreads();
#pragma unroll
  for (int i = 0; i < 4; ++i) {
    int c = c0 + ty + i * 8, r = r0 + tx;
    if (c < C && r < R) out[(size_t)c * R + r] = f2bf(tile[tx][ty + i * 8]);
  }
}

__global__ __launch_bounds__(256)
void prep_kernel(const float* __restrict__ x,
                 const float* __restrict__ sW1, const float* __restrict__ sW2,
                 const float* __restrict__ sW3, const float* __restrict__ tW,
                 const float* __restrict__ rdW, const float* __restrict__ ruW,
                 const float* __restrict__ eW,
                 const float* __restrict__ aW, const float* __restrict__ cW,
                 const float* __restrict__ ab, const float* __restrict__ cb,
                 us* __restrict__ obs, us* __restrict__ task,
                 us* __restrict__ s1t, us* __restrict__ s2t,
                 us* __restrict__ s3t, us* __restrict__ tWt,
                 us* __restrict__ rdt, us* __restrict__ rut,
                 us* __restrict__ eWt, us* __restrict__ Wh,
                 float* __restrict__ pbuf, float* __restrict__ out)
{
  __shared__ float tile[32][33];
  int b = blockIdx.x;
  const int tid = threadIdx.x;

  if (b < 64)  { transpose_tile(sW1, s1t, 128, 512, b % 16, b / 16, tile); return; }
  b -= 64;
  if (b < 256) { transpose_tile(sW2, s2t, 512, 512, b % 16, b / 16, tile); return; }
  b -= 256;
  if (b < 512) { transpose_tile(sW3, s3t, 512, 1024, b % 32, b / 32, tile); return; }
  b -= 512;
  if (b < 64)  { transpose_tile(tW, tWt, 64, 1024, b % 32, b / 32, tile); return; }
  b -= 64;
  if (b < 128) { int l = b >> 6, r = b & 63;
                 transpose_tile(rdW + (size_t)l * 65536, rdt + (size_t)l * 65536,
                                1024, 64, r % 2, r / 2, tile); return; }
  b -= 128;
  if (b < 64)  { transpose_tile(ruW, rut, 64, 1024, b % 32, b / 32, tile); return; }
  b -= 64;
  if (b < 16384) { int l = b >> 10, r = b & 1023;
                 transpose_tile(eW + (size_t)l * 1048576, eWt + (size_t)l * 1048576,
                                1024, 1024, r % 32, r / 32, tile); return; }
  b -= 16384;
  if (b < 288) {  // Wh[o][e*1024+d] = aW[e][d][o] (o<8) | cW[e][d]
    int i = b * 256 + tid;
    int o = i / 8192, k = i - o * 8192;
    float v = (o < 8) ? aW[(size_t)k * 8 + o] : cW[k];
    Wh[i] = f2bf(v);
    return;
  }
  b -= 288;
  if (b < 4096) { pbuf[(size_t)b * 256 + tid] = 0.f; return; }
  b -= 4096;
  if (b < 288) {  // out bias init (overwritten by mix_head; kept, harmless)
    int i = b * 256 + tid;
    int bb = i / 9, o = i - bb * 9;
    float s = 0.f;
    if (o < 8) { for (int e = 0; e < 8; ++e) s += ab[e * 8 + o]; }
    else       { for (int e = 0; e < 8; ++e) s += cb[e]; }
    if (o < 8) out[(size_t)bb * 8 + o] = s;
    else       out[(size_t)8192 * 8 + bb] = s;
    return;
  }
  b -= 288;
  {  // split x(B,192) -> obs (B,128), task (B,64)
    int i = b * 256 + tid;
    int bb = i / 192, c = i - bb * 192;
    us v = f2bf(x[i]);
    if (c < 128) obs[(size_t)bb * 128 + c] = v;
    else         task[(size_t)bb * 64 + (c - 128)] = v;
  }
}

// pbuf[i] += rdb[i&63]; pbf[i] = bf16(pbuf[i])
__global__ __launch_bounds__(256)
void mk_pbf(float* __restrict__ pbuf, const float* __restrict__ rdb,
            us* __restrict__ pbf, int n)
{
  int i = blockIdx.x * 256 + threadIdx.x;
  if (i >= n) return;
  float v = pbuf[i] + rdb[i & 63];
  pbuf[i] = v;
  if (pbf) pbf[i] = f2bf(v);
}

// softmax over groups of 8; groups i >= biasFrom get +bias2[(i&7)*8+j] first
__global__ __launch_bounds__(256)
void softmax8_kernel(const float* __restrict__ p, float* __restrict__ probs,
                     const float* __restrict__ bias2, int biasFrom, int total)
{
  int i = blockIdx.x * 256 + threadIdx.x;
  if (i >= total) return;
  const float4 lo = *(const float4*)(p + (size_t)i * 8);
  const float4 hi = *(const float4*)(p + (size_t)i * 8 + 4);
  float v[8] = { lo.x, lo.y, lo.z, lo.w, hi.x, hi.y, hi.z, hi.w };
  if (i >= biasFrom) {
    const float* bb = bias2 + (i & 7) * 8;
#pragma unroll
    for (int j = 0; j < 8; ++j) v[j] += bb[j];
  }
  float m = v[0];
#pragma unroll
  for (int j = 1; j < 8; ++j) m = fmaxf(m, v[j]);
  float s = 0.f;
#pragma unroll
  for (int j = 0; j < 8; ++j) { v[j] = __expf(v[j] - m); s += v[j]; }
  float inv = 1.f / s;
  float4 olo = { v[0]*inv, v[1]*inv, v[2]*inv, v[3]*inv };
  float4 ohi = { v[4]*inv, v[5]*inv, v[6]*inv, v[7]*inv };
  *(float4*)(probs + (size_t)i * 8)     = olo;
  *(float4*)(probs + (size_t)i * 8 + 4) = ohi;
}

// out[i*sOutE + bl*sOutB + d] = sum_j P[bg,i,j]*he[j,bl,d]; block per local b
__global__ __launch_bounds__(256)
void mix_kernel(const us* __restrict__ he, const float* __restrict__ probs_l,
                us* __restrict__ xx, int b0, int chunkB,
                long long sOutE, long long sOutB)
{
  const int bl = blockIdx.x;
  const int bg = b0 + bl;
  __shared__ float P[64];
  if (threadIdx.x < 64) P[threadIdx.x] = probs_l[(size_t)bg * 64 + threadIdx.x];
  __syncthreads();
  const int t = threadIdx.x;
  const size_t es = (size_t)chunkB * 1024;
  const size_t rbase = (size_t)bl * 1024 + (size_t)t * 4;
  const size_t wbase = (size_t)bl * sOutB + (size_t)t * 4;
  float hv[8][4];
#pragma unroll
  for (int j = 0; j < 8; ++j) {
    ushort4 h4 = *(const ushort4*)(he + (size_t)j * es + rbase);
    hv[j][0] = bf2f(h4.x); hv[j][1] = bf2f(h4.y);
    hv[j][2] = bf2f(h4.z); hv[j][3] = bf2f(h4.w);
  }
#pragma unroll
  for (int i = 0; i < 8; ++i) {
    float o0 = 0.f, o1 = 0.f, o2 = 0.f, o3 = 0.f;
#pragma unroll
    for (int j = 0; j < 8; ++j) {
      float pij = P[i * 8 + j];
      o0 += pij * hv[j][0]; o1 += pij * hv[j][1];
      o2 += pij * hv[j][2]; o3 += pij * hv[j][3];
    }
    ushort4 ov = { f2bf(o0), f2bf(o1), f2bf(o2), f2bf(o3) };
    *(ushort4*)(xx + (size_t)i * sOutE + wbase) = ov;
  }
}

// ---------------------------------------------------------------------------
// mix_head: fused second mix + policy/value heads.  2 batch rows per block.
// Each thread covers d = t*4..t*4+3 for all 8 experts (32 k-elems of the
// 8192-long head reduction); the block covers the whole reduction for both
// rows.  Mix stays in fp32.  Wave shuffle-reduce + cross-wave LDS reduce.
// out: mu = out[bg*8+o] (o<8), values = out[Btot*8+bg].
// ---------------------------------------------------------------------------
__global__ __launch_bounds__(256)
void mix_head_kernel(const us* __restrict__ he, const float* __restrict__ probs_l,
                     const us* __restrict__ Wh, const float* __restrict__ ab,
                     const float* __restrict__ cb, float* __restrict__ out,
                     int b0, int chunkB, int Btot)
{
  const int r0 = blockIdx.x * 2;            // local row pair
  const int t = threadIdx.x;
  const int lane = t & 63;
  const int wave = t >> 6;
  __shared__ float P[2][64];
  __shared__ float red[2][9][4];
  if (t < 128)
    P[t >> 6][t & 63] = probs_l[(size_t)(b0 + r0 + (t >> 6)) * 64 + (t & 63)];
  __syncthreads();

  const size_t es = (size_t)chunkB * 1024;
  float xv[2][8][4];
#pragma unroll
  for (int r = 0; r < 2; ++r) {
#pragma unroll
    for (int i = 0; i < 8; ++i)
#pragma unroll
      for (int q = 0; q < 4; ++q) xv[r][i][q] = 0.f;
    const size_t rbase = (size_t)(r0 + r) * 1024 + (size_t)t * 4;
#pragma unroll
    for (int j = 0; j < 8; ++j) {
      ushort4 h4 = *(const ushort4*)(he + (size_t)j * es + rbase);
      float h0 = bf2f(h4.x), h1 = bf2f(h4.y), h2 = bf2f(h4.z), h3 = bf2f(h4.w);
#pragma unroll
      for (int i = 0; i < 8; ++i) {
        float p = P[r][i * 8 + j];
        xv[r][i][0] += p * h0; xv[r][i][1] += p * h1;
        xv[r][i][2] += p * h2; xv[r][i][3] += p * h3;
      }
    }
  }

  // head: s[r][o] = sum_{i,q} xv[r][i][q] * Wh[o][i*1024 + t*4 + q]
  float s[2][9];
#pragma unroll
  for (int o = 0; o < 9; ++o) { s[0][o] = 0.f; s[1][o] = 0.f; }
#pragma unroll
  for (int o = 0; o < 9; ++o) {
    const us* w = Wh + (size_t)o * 8192 + (size_t)t * 4;
#pragma unroll
    for (int i = 0; i < 8; ++i) {
      ushort4 w4 = *(const ushort4*)(w + i * 1024);
      float w0 = bf2f(w4.x), w1 = bf2f(w4.y), w2 = bf2f(w4.z), w3 = bf2f(w4.w);
      s[0][o] += xv[0][i][0]*w0 + xv[0][i][1]*w1 + xv[0][i][2]*w2 + xv[0][i][3]*w3;
      s[1][o] += xv[1][i][0]*w0 + xv[1][i][1]*w1 + xv[1][i][2]*w2 + xv[1][i][3]*w3;
    }
  }

  // wave shuffle-reduce (64-wide), then cross-wave via LDS
#pragma unroll
  for (int off = 32; off >= 1; off >>= 1) {
#pragma unroll
    for (int r = 0; r < 2; ++r)
#pragma unroll
      for (int o = 0; o < 9; ++o) s[r][o] += __shfl_down(s[r][o], off);
  }
  if (lane == 0) {
#pragma unroll
    for (int r = 0; r < 2; ++r)
#pragma unroll
      for (int o = 0; o < 9; ++o) red[r][o][wave] = s[r][o];
  }
  __syncthreads();
  if (t < 18) {
    int r = t / 9, o = t - r * 9;
    float v = red[r][o][0] + red[r][o][1] + red[r][o][2] + red[r][o][3];
    float bias = 0.f;
    if (o < 8) { for (int e = 0; e < 8; ++e) bias += ab[e * 8 + o]; }
    else       { for (int e = 0; e < 8; ++e) bias += cb[e]; }
    int bg = b0 + r0 + r;
    if (o < 8) out[(size_t)bg * 8 + o] = v + bias;
    else       out[(size_t)Btot * 8 + bg] = v + bias;
  }
}

// ---------------------------------------------------------------------------
extern "C" void kernel_launch(void* const* d_in, const int* in_sizes, int n_in,
                              void* d_out, int out_size, void* d_ws, size_t ws_size,
                              hipStream_t stream)
{
  const float* x   = (const float*)d_in[0];
  const float* sW1 = (const float*)d_in[1];
  const float* sb1 = (const float*)d_in[2];
  const float* sW2 = (const float*)d_in[3];
  const float* sb2 = (const float*)d_in[4];
  const float* sW3 = (const float*)d_in[5];
  const float* sb3 = (const float*)d_in[6];
  const float* tW  = (const float*)d_in[7];
  const float* tb  = (const float*)d_in[8];
  const float* rdW = (const float*)d_in[9];
  const float* rdb = (const float*)d_in[10];
  const float* ruW = (const float*)d_in[11];
  const float* rub = (const float*)d_in[12];
  const float* eW  = (const float*)d_in[13];
  const float* eb  = (const float*)d_in[14];
  const float* aW  = (const float*)d_in[15];
  const float* ab  = (const float*)d_in[16];
  const float* cW  = (const float*)d_in[17];
  const float* cb  = (const float*)d_in[18];
  float* out = (float*)d_out;

  const int B = 8192;
  const size_t BD = (size_t)B * 1024;
  char* ws = (char*)d_ws;

  // ---- arena: persistent region -------------------------------------------
  size_t o = 0;
  auto take = [&](size_t bytes) { size_t r = o; o = (o + bytes + 255) & ~(size_t)255; return r; };
  const size_t off_s1t  = take((size_t)512 * 128 * 2);
  const size_t off_s2t  = take((size_t)512 * 512 * 2);
  const size_t off_s3t  = take((size_t)1024 * 512 * 2);
  const size_t off_tWt  = take((size_t)1024 * 64 * 2);
  const size_t off_rdt  = take((size_t)2 * 64 * 1024 * 2);
  const size_t off_rut  = take((size_t)1024 * 64 * 2);
  const size_t off_eWt  = take((size_t)16 * 1024 * 1024 * 2);
  const size_t off_fobs = take(BD * 2);
  const size_t off_probs= take((size_t)2 * B * 64 * 4);
  const size_t off_Wh   = take((size_t)9 * 8192 * 2);
  const size_t P0 = o;
  // ---- scratch overlays (routing phase) -----------------------------------
  const size_t off_rin  = P0;                 // also h1
  const size_t off_rbuf = off_rin + BD * 2;   // also h2, u
  const size_t off_pbuf = off_rbuf + BD * 2;
  const size_t off_pbf  = off_pbuf + (size_t)2 * B * 64 * 4;
  const size_t off_obs  = off_pbf + (size_t)B * 64 * 2;
  const size_t off_task = off_obs + (size_t)B * 128 * 2;
  const size_t routing_end = off_task + (size_t)B * 64 * 2;

  // ---- expert-stage chunk selection (he/xx overlay scratch at P0) ---------
  int chunk = 0;
  const int cands[4] = {8192, 4096, 2048, 1024};
  for (int i = 0; i < 4; ++i) {
    size_t need = P0 + (size_t)cands[i] * 32768;  // he + xx
    if (need <= ws_size) { chunk = cands[i]; break; }
  }
  if (!chunk || routing_end > ws_size) return;

  us* s1t  = (us*)(ws + off_s1t);
  us* s2t  = (us*)(ws + off_s2t);
  us* s3t  = (us*)(ws + off_s3t);
  us* tWt  = (us*)(ws + off_tWt);
  us* rdt  = (us*)(ws + off_rdt);
  us* rut  = (us*)(ws + off_rut);
  us* eWt  = (us*)(ws + off_eWt);
  us* fobs = (us*)(ws + off_fobs);
  float* probs = (float*)(ws + off_probs);
  us* Wh   = (us*)(ws + off_Wh);
  us* rin  = (us*)(ws + off_rin);
  us* rbuf = (us*)(ws + off_rbuf);
  float* pbuf = (float*)(ws + off_pbuf);
  us* pbf  = (us*)(ws + off_pbf);
  us* obs_bf  = (us*)(ws + off_obs);
  us* task_bf = (us*)(ws + off_task);
  us* h1 = rin;
  us* h2 = rbuf;
  us* he = (us*)(ws + P0);
  us* xx = (us*)(ws + P0 + (size_t)chunk * 16384);

  // ---- fused prep: transposes + Wh + pbuf zero + out bias + x split -------
  prep_kernel<<<dim3(28288), 256, 0, stream>>>(x, sW1, sW2, sW3, tW, rdW, ruW,
      eW, aW, cW, ab, cb, obs_bf, task_bf, s1t, s2t, s3t, tWt, rdt, rut,
      eWt, Wh, pbuf, out);

  // ---- shared MLP ---------------------------------------------------------
  gemm_main<true, true, false, false, false><<<dim3(4, 64, 1), 256, 0, stream>>>(
      obs_bf, s1t, sb1, h1, (us*)0, (const us*)0, 512, 128, 128, 128, 0, 0, 0, 0);
  gemm_main<true, true, false, false, false><<<dim3(4, 64, 1), 256, 0, stream>>>(
      h1, s2t, sb2, h2, (us*)0, (const us*)0, 512, 512, 512, 512, 0, 0, 0, 0);
  gemm_main<true, false, false, false, false><<<dim3(8, 64, 1), 256, 0, stream>>>(
      h2, s3t, sb3, fobs, (us*)0, (const us*)0, 1024, 512, 512, 512, 0, 0, 0, 0);
  // z-GEMM fused: rin = relu(task@tW+tb)*fobs ; rbuf = relu(rin)
  gemm_main<true, true, true, false, true><<<dim3(8, 64, 1), 256, 0, stream>>>(
      task_bf, tWt, tb, rin, rbuf, fobs, 1024, 64, 64, 64, 0, 0, 0, 0);

  // ---- routing (layers 0,1; layer 2 is dead code) -------------------------
  gemm_splitk<<<dim3(1, 64, 4), 256, 0, stream>>>(rbuf, rdt, pbuf,
      64, 256, 1024, 1024, 256, 256, 0, 0, 0);                       // p0
  mk_pbf<<<dim3((B * 64 + 255) / 256), 256, 0, stream>>>(pbuf, rdb, pbf, B * 64);
  // u-GEMM fused: rbuf = relu((pbf@ruW+rub) * rin)
  gemm_main<true, false, true, true, false><<<dim3(8, 64, 1), 256, 0, stream>>>(
      pbf, rut, rub, rbuf, (us*)0, rin, 1024, 64, 64, 64, 0, 0, 0, 0);
  gemm_splitk<<<dim3(1, 64, 4), 256, 0, stream>>>(rbuf, rdt + 65536,
      pbuf + (size_t)B * 64, 64, 256, 1024, 1024, 256, 256, 0, 0, 0); // p1
  softmax8_kernel<<<dim3((2 * B * 8 + 255) / 256), 256, 0, stream>>>(
      pbuf, probs, rdb + 64, B * 8, 2 * B * 8);

  // ---- expert stage, chunked over batch -----------------------------------
  // expert GEMMs on gemm_p128 (chunk%128==0 always; K=1024 -> NP=32 even)
  const long long sHE = (long long)chunk * 1024;
  for (int b0 = 0; b0 < B; b0 += chunk) {
    gemm_p128<true, true><<<dim3(8, chunk / 128, 8), 256, 0, stream>>>(
        fobs + (size_t)b0 * 1024, eWt, eb, he,
        1024, 1024, 1024, 1024, 0, 1048576, 1024, sHE);
    mix_kernel<<<dim3(chunk), 256, 0, stream>>>(he, probs, xx, b0, chunk, sHE, 1024);
    gemm_p128<true, true><<<dim3(8, chunk / 128, 8), 256, 0, stream>>>(
        xx, eWt + (size_t)8 * 1048576, eb + 8192, he,
        1024, 1024, 1024, 1024, sHE, 1048576, 1024, sHE);
    // fused second mix + heads: no xx b-major materialization, no atomics
    mix_head_kernel<<<dim3(chunk / 2), 256, 0, stream>>>(
        he, probs + (size_t)B * 64, Wh, ab, cb, out, b0, chunk, B);
  }
}

// Round 4
// 692.852 us; speedup vs baseline: 1.1006x; 1.1006x over previous
//
#include <hip/hip_runtime.h>

// ---------------------------------------------------------------------------
// SharedPPOSoftModularizedMLP on MI355X (gfx950)
// B=8192, OBS=128, TASK=64, D=1024, E=8, L=4
// bf16 MFMA (16x16x32), fp32 accumulate.
// R12: expert GEMMs -> gemm_k64: 256x256 tile, 8 waves, BK=64 double-buffer
//      (128KB LDS), ONE vmcnt(0)+barrier per K-tile (16 sync points, not 32),
//      B-frags read once per tile, A-frag ds_reads issued between 16-MFMA
//      clusters (overlap LDS latency under MFMA), staging spread 1 half-tile
//      per cluster.  Waves free-run within a tile (no intra-tile barrier) so
//      the LDS pipe and matrix pipe overlap across waves.  R11's 128-tile
//      (regression: 2x traffic per MFMA) reverted.  Tail unchanged from R10.
// ---------------------------------------------------------------------------

typedef __attribute__((ext_vector_type(8))) short short8;   // 8 x bf16 frag
typedef __attribute__((ext_vector_type(4))) float floatx4;  // MFMA acc
typedef unsigned short us;

__device__ __forceinline__ us f2bf(float f) {
  union { float f; unsigned u; } v; v.f = f;
  return (us)((v.u + 0x7FFFu + ((v.u >> 16) & 1u)) >> 16);  // RNE
}
__device__ __forceinline__ float bf2f(us h) {
  union { unsigned u; float f; } v; v.u = ((unsigned)h) << 16;
  return v.f;
}

// async global->LDS, 16B per lane; lds dest = wave-uniform base + lane*16
__device__ __forceinline__ void g2lds16(const void* g, void* l) {
  __builtin_amdgcn_global_load_lds(
      (const __attribute__((address_space(1))) void*)g,
      (__attribute__((address_space(3))) void*)l, 16, 0, 0);
}

// ---------------------------------------------------------------------------
// Main-path GEMM: C[M,N] = post(act(A@Bt^T + bias)); all bf16, M,N %128==0.
// post: MUL -> elementwise * Mul[M,N]; RELU2 -> relu after MUL.
// CB2: Cb = value, Cb2 = relu(value).
// grid=(N/128, M/128, E). XCD chunk swizzle when total blocks % 8 == 0.
// ---------------------------------------------------------------------------
template<bool BIAS, bool RELU, bool MUL, bool RELU2, bool CB2>
__global__ __launch_bounds__(256)
void gemm_main(const us* __restrict__ A, const us* __restrict__ Bt,
               const float* __restrict__ bias,
               us* __restrict__ Cb, us* __restrict__ Cb2,
               const us* __restrict__ Mul,
               int N, int K, int lda, int ldb,
               long long sA, long long sB, long long sBias, long long sC)
{
  // ---- XCD chunk swizzle ----
  int bx = blockIdx.x, by = blockIdx.y, bz = blockIdx.z;
  {
    const int gx = gridDim.x, gy = gridDim.y;
    const int total = gx * gy * gridDim.z;
    if ((total & 7) == 0) {
      int L = bx + gx * (by + gy * bz);
      int per = total >> 3;
      int w = (L & 7) * per + (L >> 3);
      bx = w % gx; w /= gx;
      by = w % gy; bz = w / gy;
    }
  }

  const int e = bz;
  const us* Ab = A + (size_t)e * sA;
  const us* Bb = Bt + (size_t)e * sB;

  const int m0 = by * 128;
  const int n0 = bx * 128;
  const int tid = threadIdx.x;
  const int wave = tid >> 6;
  const int lane = tid & 63;
  const int wm = (wave >> 1) * 64;
  const int wn = (wave & 1) * 64;
  const int lr = lane & 15;
  const int lq = lane >> 4;

  // staging: A = smem[0..8191], B = smem[8192..16383]  (us units)
  // epilogue tile: smem[0..17407] as [128][136] us  (R4 layout)
  __shared__ __align__(16) us smem[128 * 136 + 64];
  us* ldsA = smem;
  us* ldsB = smem + 128 * 64;

  floatx4 acc[4][4];
#pragma unroll
  for (int i = 0; i < 4; ++i)
#pragma unroll
    for (int j = 0; j < 4; ++j) acc[i][j] = (floatx4){0.f, 0.f, 0.f, 0.f};

  for (int k0 = 0; k0 < K; k0 += 64) {
#pragma unroll
    for (int c = 0; c < 4; ++c) {
      int slot = c * 256 + tid;               // physical 16B chunk
      int r = slot >> 3;
      int s = (slot & 7) ^ (r & 7);           // logical slab (XOR swizzle)
      int ubase = (c * 256 + wave * 64) * 8;  // wave-uniform LDS base (us)
      g2lds16(Ab + (size_t)(m0 + r) * lda + k0 + s * 8, ldsA + ubase);
      g2lds16(Bb + (size_t)(n0 + r) * ldb + k0 + s * 8, ldsB + ubase);
    }
    __syncthreads();

#pragma unroll
    for (int kk = 0; kk < 2; ++kk) {
      short8 af[4], bfr[4];
#pragma unroll
      for (int t = 0; t < 4; ++t) {
        int m = wm + t * 16 + lr;
        int s = kk * 4 + lq;
        af[t]  = *(const short8*)(ldsA + (size_t)(m * 8 + (s ^ (m & 7))) * 8);
        int n = wn + t * 16 + lr;
        bfr[t] = *(const short8*)(ldsB + (size_t)(n * 8 + (s ^ (n & 7))) * 8);
      }
#pragma unroll
      for (int mt = 0; mt < 4; ++mt)
#pragma unroll
        for (int nt = 0; nt < 4; ++nt)
          acc[mt][nt] = __builtin_amdgcn_mfma_f32_16x16x32_bf16(
              af[mt], bfr[nt], acc[mt][nt], 0, 0, 0);
    }
    __syncthreads();
  }

  // ---- epilogue (R4): stage bf16 tile in LDS [128][136], store dwordx4 ----
  // C/D layout: col = lane&15, row = lq*4 + r
#pragma unroll
  for (int nt = 0; nt < 4; ++nt) {
    int coll = wn + nt * 16 + lr;
    int col = n0 + coll;
    float bv = BIAS ? bias[(size_t)e * sBias + col] : 0.f;
#pragma unroll
    for (int mt = 0; mt < 4; ++mt) {
      int rowb = wm + mt * 16 + lq * 4;
#pragma unroll
      for (int r = 0; r < 4; ++r) {
        int rowl = rowb + r;
        float v = acc[mt][nt][r] + bv;
        if (RELU) v = fmaxf(v, 0.f);
        if (MUL) v *= bf2f(Mul[(size_t)(m0 + rowl) * N + col]);
        if (RELU2) v = fmaxf(v, 0.f);
        smem[rowl * 136 + coll] = f2bf(v);
      }
    }
  }
  __syncthreads();
#pragma unroll
  for (int c = 0; c < 8; ++c) {
    int sl = c * 256 + tid;
    int rowl = sl >> 4;
    int seg = sl & 15;
    short8 val = *(const short8*)(smem + rowl * 136 + seg * 8);
    size_t gidx = (size_t)e * sC + (size_t)(m0 + rowl) * N + n0 + seg * 8;
    *(short8*)(Cb + gidx) = val;
    if (CB2) {
      short8 rl;
#pragma unroll
      for (int q = 0; q < 8; ++q) {
        us u = (us)val[q];
        rl[q] = (short)((u & 0x8000u) ? (us)0 : u);
      }
      *(short8*)(Cb2 + gidx) = rl;
    }
  }
}

// ---------------------------------------------------------------------------
// gemm_k64: 256x256-tile GEMM, BK=64 double-buffer, 1 sync per K-tile.
//   C[M,N] = relu?(A@Bt^T + bias), bf16 in/out, fp32 acc.
//   Requirements: M%256==0, N%256==0, K%64==0, K>=128.
//   grid = (N/256, M/256, E), block = 512 (8 waves, 2M x 4N; 128x64/wave).
// Per K-tile t (buf b=t&1): 4 clusters, each {stage 1 half-tile of t+1 into
// buf b^1 (2 g2lds); ds_read 4 A-frags (+8 B-frags in cluster 0); 16 MFMA}.
// Boundary: vmcnt(0) [all 8 of t+1's loads landed -- nothing else in flight,
// so 0 IS the counted value] + s_barrier + sched_barrier.  No intra-tile
// barrier: waves free-run, so one wave's ds_reads overlap another's MFMAs,
// and each wave's cluster-j+1 reads issue under its own cluster-j MFMAs.
// LDS layout per buf: rows 0..255 x 64 k; element (row, slab s=16B unit)
// at us-offset row*64 + ((s ^ (row&7))<<3)  [proven conflict-free, R10].
// WAR safety: wave's tile-t ds_reads complete before its last MFMA (compiler
// lgkmcnt), which precedes its boundary barrier -> stages into b^1 at tile
// t+1 cannot overwrite unread data.
// ---------------------------------------------------------------------------
template<bool BIAS, bool RELU>
__global__ __launch_bounds__(512, 2)
void gemm_k64(const us* __restrict__ A, const us* __restrict__ Bt,
              const float* __restrict__ bias, us* __restrict__ Cb,
              int N, int K, int lda, int ldb,
              long long sA, long long sB, long long sBias, long long sC)
{
  // ---- XCD chunk swizzle (grid here is always %8==0) ----
  int bx = blockIdx.x, by = blockIdx.y, bz = blockIdx.z;
  {
    const int gx = gridDim.x, gy = gridDim.y;
    const int total = gx * gy * gridDim.z;
    if ((total & 7) == 0) {
      int L = bx + gx * (by + gy * bz);
      int per = total >> 3;
      int w = (L & 7) * per + (L >> 3);
      bx = w % gx; w /= gx;
      by = w % gy; bz = w / gy;
    }
  }
  const int e = bz;
  const us* Ab = A + (size_t)e * sA;
  const us* Bb = Bt + (size_t)e * sB;

  const int m0 = by * 256;
  const int n0 = bx * 256;
  const int tid  = threadIdx.x;
  const int wave = tid >> 6;
  const int lane = tid & 63;
  const int wm = (wave >> 2) * 128;   // 2 M-waves x 128 rows
  const int wn = (wave & 3) * 64;     // 4 N-waves x 64 cols
  const int lr = lane & 15;
  const int lq = lane >> 4;

  // A bufs at [b*16384], B bufs at [32768 + b*16384] (us units), 128KB total.
  // Epilogue reuses the 128KB as a swizzled [256][256] us tile.
  __shared__ __align__(16) us smem[65536];

  floatx4 acc[8][4];
#pragma unroll
  for (int i = 0; i < 8; ++i)
#pragma unroll
    for (int j = 0; j < 4; ++j) acc[i][j] = (floatx4){0.f, 0.f, 0.f, 0.f};

  // ---- staging source pointers --------------------------------------------
  // Half-tile = 128 rows x 64 k = 8192 us = 1024 chunks of 16B.
  // Chunk c: row = c>>3, pos = c&7, global slab = pos ^ (row&7).
  // Thread covers c0 = tid and c1 = tid+512; half1 adds +128 rows.
  const us *pA0, *pA1, *pB0, *pB1;
  {
    int c = tid, r = c >> 3, s = (c & 7) ^ (r & 7);
    pA0 = Ab + (size_t)(m0 + r) * lda + s * 8;
    pB0 = Bb + (size_t)(n0 + r) * ldb + s * 8;
    c = tid + 512; r = c >> 3; s = (c & 7) ^ (r & 7);
    pA1 = Ab + (size_t)(m0 + r) * lda + s * 8;
    pB1 = Bb + (size_t)(n0 + r) * ldb + s * 8;
  }
  const size_t h1a = (size_t)128 * lda;   // +128 rows (A)
  const size_t h1b = (size_t)128 * ldb;   // +128 rows (B)
  const int dwave = wave * 512;           // wave-uniform LDS chunk base (us)

  // half: 0 = rows 0..127, 1 = rows 128..255.  koff in elements.
  auto stageA = [&](int buf, int half, int koff) {
    us* dst = smem + buf * 16384 + half * 8192 + dwave;
    const us* p0 = pA0 + (half ? h1a : 0) + koff;
    const us* p1 = pA1 + (half ? h1a : 0) + koff;
    g2lds16(p0, dst);
    g2lds16(p1, dst + 4096);
  };
  auto stageB = [&](int buf, int half, int koff) {
    us* dst = smem + 32768 + buf * 16384 + half * 8192 + dwave;
    const us* p0 = pB0 + (half ? h1b : 0) + koff;
    const us* p1 = pB1 + (half ? h1b : 0) + koff;
    g2lds16(p0, dst);
    g2lds16(p1, dst + 4096);
  };

  // ---- per-lane fragment read offsets (kk=0; kk=1 is ^32) ----
  int offA[8], offB[4];
#pragma unroll
  for (int t = 0; t < 8; ++t) {
    int m = wm + t * 16 + lr;
    offA[t] = m * 64 + ((lq ^ (m & 7)) << 3);
  }
#pragma unroll
  for (int t = 0; t < 4; ++t) {
    int n = wn + t * 16 + lr;
    offB[t] = n * 64 + ((lq ^ (n & 7)) << 3);
  }

  // ---- prologue: stage tile 0 into buf 0, drain, publish ----
  stageA(0, 0, 0); stageB(0, 0, 0); stageA(0, 1, 0); stageB(0, 1, 0);
  asm volatile("s_waitcnt vmcnt(0)" ::: "memory");
  __builtin_amdgcn_s_barrier();
  __builtin_amdgcn_sched_barrier(0);

  const int NT = K >> 6;              // K-tiles (>=2 by contract)
  for (int t = 0; t < NT; ++t) {
    const int b = t & 1;
    const us* a  = smem + b * 16384;
    const us* bb = smem + 32768 + b * 16384;
    const int nb = b ^ 1;
    const int ko = (t + 1) << 6;
    const bool pf = (t + 1 < NT);

    short8 Bf0[4], Bf1[4];            // B frags, kk=0 / kk=1 (whole tile)
    short8 a00, a01, a10, a11;        // A frags for current cluster

    // ---- cluster 0: mt 0,1 (+ B reads) ----
    if (pf) stageA(nb, 0, ko);
#pragma unroll
    for (int nt = 0; nt < 4; ++nt) {
      Bf0[nt] = *(const short8*)(bb + offB[nt]);
      Bf1[nt] = *(const short8*)(bb + (offB[nt] ^ 32));
    }
    a00 = *(const short8*)(a + offA[0]); a01 = *(const short8*)(a + (offA[0] ^ 32));
    a10 = *(const short8*)(a + offA[1]); a11 = *(const short8*)(a + (offA[1] ^ 32));
    __builtin_amdgcn_s_setprio(1);
#pragma unroll
    for (int nt = 0; nt < 4; ++nt) {
      acc[0][nt] = __builtin_amdgcn_mfma_f32_16x16x32_bf16(a00, Bf0[nt], acc[0][nt], 0, 0, 0);
      acc[1][nt] = __builtin_amdgcn_mfma_f32_16x16x32_bf16(a10, Bf0[nt], acc[1][nt], 0, 0, 0);
    }
#pragma unroll
    for (int nt = 0; nt < 4; ++nt) {
      acc[0][nt] = __builtin_amdgcn_mfma_f32_16x16x32_bf16(a01, Bf1[nt], acc[0][nt], 0, 0, 0);
      acc[1][nt] = __builtin_amdgcn_mfma_f32_16x16x32_bf16(a11, Bf1[nt], acc[1][nt], 0, 0, 0);
    }
    __builtin_amdgcn_s_setprio(0);

    // ---- cluster 1: mt 2,3 ----
    if (pf) stageB(nb, 0, ko);
    a00 = *(const short8*)(a + offA[2]); a01 = *(const short8*)(a + (offA[2] ^ 32));
    a10 = *(const short8*)(a + offA[3]); a11 = *(const short8*)(a + (offA[3] ^ 32));
    __builtin_amdgcn_s_setprio(1);
#pragma unroll
    for (int nt = 0; nt < 4; ++nt) {
      acc[2][nt] = __builtin_amdgcn_mfma_f32_16x16x32_bf16(a00, Bf0[nt], acc[2][nt], 0, 0, 0);
      acc[3][nt] = __builtin_amdgcn_mfma_f32_16x16x32_bf16(a10, Bf0[nt], acc[3][nt], 0, 0, 0);
    }
#pragma unroll
    for (int nt = 0; nt < 4; ++nt) {
      acc[2][nt] = __builtin_amdgcn_mfma_f32_16x16x32_bf16(a01, Bf1[nt], acc[2][nt], 0, 0, 0);
      acc[3][nt] = __builtin_amdgcn_mfma_f32_16x16x32_bf16(a11, Bf1[nt], acc[3][nt], 0, 0, 0);
    }
    __builtin_amdgcn_s_setprio(0);

    // ---- cluster 2: mt 4,5 ----
    if (pf) stageA(nb, 1, ko);
    a00 = *(const short8*)(a + offA[4]); a01 = *(const short8*)(a + (offA[4] ^ 32));
    a10 = *(const short8*)(a + offA[5]); a11 = *(const short8*)(a + (offA[5] ^ 32));
    __builtin_amdgcn_s_setprio(1);
#pragma unroll
    for (int nt = 0; nt < 4; ++nt) {
      acc[4][nt] = __builtin_amdgcn_mfma_f32_16x16x32_bf16(a00, Bf0[nt], acc[4][nt], 0, 0, 0);
      acc[5][nt] = __builtin_amdgcn_mfma_f32_16x16x32_bf16(a10, Bf0[nt], acc[5][nt], 0, 0, 0);
    }
#pragma unroll
    for (int nt = 0; nt < 4; ++nt) {
      acc[4][nt] = __builtin_amdgcn_mfma_f32_16x16x32_bf16(a01, Bf1[nt], acc[4][nt], 0, 0, 0);
      acc[5][nt] = __builtin_amdgcn_mfma_f32_16x16x32_bf16(a11, Bf1[nt], acc[5][nt], 0, 0, 0);
    }
    __builtin_amdgcn_s_setprio(0);

    // ---- cluster 3: mt 6,7 ----
    if (pf) stageB(nb, 1, ko);
    a00 = *(const short8*)(a + offA[6]); a01 = *(const short8*)(a + (offA[6] ^ 32));
    a10 = *(const short8*)(a + offA[7]); a11 = *(const short8*)(a + (offA[7] ^ 32));
    __builtin_amdgcn_s_setprio(1);
#pragma unroll
    for (int nt = 0; nt < 4; ++nt) {
      acc[6][nt] = __builtin_amdgcn_mfma_f32_16x16x32_bf16(a00, Bf0[nt], acc[6][nt], 0, 0, 0);
      acc[7][nt] = __builtin_amdgcn_mfma_f32_16x16x32_bf16(a10, Bf0[nt], acc[7][nt], 0, 0, 0);
    }
#pragma unroll
    for (int nt = 0; nt < 4; ++nt) {
      acc[6][nt] = __builtin_amdgcn_mfma_f32_16x16x32_bf16(a01, Bf1[nt], acc[6][nt], 0, 0, 0);
      acc[7][nt] = __builtin_amdgcn_mfma_f32_16x16x32_bf16(a11, Bf1[nt], acc[7][nt], 0, 0, 0);
    }
    __builtin_amdgcn_s_setprio(0);

    // ---- K-tile boundary: tile t+1 fully landed, publish to all waves ----
    if (pf) {
      asm volatile("s_waitcnt vmcnt(0)" ::: "memory");
      __builtin_amdgcn_s_barrier();
      __builtin_amdgcn_sched_barrier(0);
    }
  }

  // ---- epilogue: bias+relu, bf16 via swizzled LDS [256][256], 16B stores --
  __syncthreads();
#pragma unroll
  for (int nt = 0; nt < 4; ++nt) {
    int coll = wn + nt * 16 + lr;
    float bv = BIAS ? bias[(size_t)e * sBias + n0 + coll] : 0.f;
#pragma unroll
    for (int mt = 0; mt < 8; ++mt) {
      int rowb = wm + mt * 16 + lq * 4;
#pragma unroll
      for (int r = 0; r < 4; ++r) {
        int row = rowb + r;
        float v = acc[mt][nt][r] + bv;
        if (RELU) v = fmaxf(v, 0.f);
        smem[row * 256 + (coll ^ (((row >> 2) & 3) << 4))] = f2bf(v);
      }
    }
  }
  __syncthreads();
#pragma unroll
  for (int c = 0; c < 16; ++c) {
    int sl  = c * 512 + tid;
    int row = sl >> 5;
    int ch  = sl & 31;
    short8 val = *(const short8*)(smem + row * 256 +
                                  ((ch * 8) ^ (((row >> 2) & 3) << 4)));
    *(short8*)(Cb + (size_t)e * sC + (size_t)(m0 + row) * N + n0 + ch * 8) = val;
  }
}

// ---------------------------------------------------------------------------
// Split-K GEMM: atomicAdd fp32 partials.  blockIdx.z = k-chunk (offset by
// sA/sB).  N may be < 128 (B-row clamp).  Used for routing p0/p1 (N=64).
// ---------------------------------------------------------------------------
__global__ __launch_bounds__(256)
void gemm_splitk(const us* __restrict__ A, const us* __restrict__ Bt,
                 float* __restrict__ Cf,
                 int N, int K, int lda, int ldb,
                 long long sA, long long sB,
                 int headout, int rowoff, int Btot)
{
  int bx = blockIdx.x, by = blockIdx.y, bz = blockIdx.z;
  {
    const int gx = gridDim.x, gy = gridDim.y;
    const int total = gx * gy * gridDim.z;
    if ((total & 7) == 0) {
      int L = bx + gx * (by + gy * bz);
      int per = total >> 3;
      int w = (L & 7) * per + (L >> 3);
      bx = w % gx; w /= gx;
      by = w % gy; bz = w / gy;
    }
  }

  const us* Ab = A + (size_t)bz * sA;
  const us* Bb = Bt + (size_t)bz * sB;

  const int m0 = by * 128;
  const int n0 = bx * 128;
  const int tid = threadIdx.x;
  const int wave = tid >> 6;
  const int lane = tid & 63;
  const int wm = (wave >> 1) * 64;
  const int wn = (wave & 1) * 64;
  const int lr = lane & 15;
  const int lq = lane >> 4;

  __shared__ __align__(16) us smem[128 * 128];
  us* ldsA = smem;
  us* ldsB = smem + 128 * 64;

  floatx4 acc[4][4];
#pragma unroll
  for (int i = 0; i < 4; ++i)
#pragma unroll
    for (int j = 0; j < 4; ++j) acc[i][j] = (floatx4){0.f, 0.f, 0.f, 0.f};

  for (int k0 = 0; k0 < K; k0 += 64) {
#pragma unroll
    for (int c = 0; c < 4; ++c) {
      int slot = c * 256 + tid;
      int r = slot >> 3;
      int s = (slot & 7) ^ (r & 7);
      int ubase = (c * 256 + wave * 64) * 8;
      g2lds16(Ab + (size_t)(m0 + r) * lda + k0 + s * 8, ldsA + ubase);
      int nrow = n0 + r; if (nrow > N - 1) nrow = N - 1;  // clamp (N<128)
      g2lds16(Bb + (size_t)nrow * ldb + k0 + s * 8, ldsB + ubase);
    }
    __syncthreads();

#pragma unroll
    for (int kk = 0; kk < 2; ++kk) {
      short8 af[4], bfr[4];
#pragma unroll
      for (int t = 0; t < 4; ++t) {
        int m = wm + t * 16 + lr;
        int s = kk * 4 + lq;
        af[t]  = *(const short8*)(ldsA + (size_t)(m * 8 + (s ^ (m & 7))) * 8);
        int n = wn + t * 16 + lr;
        bfr[t] = *(const short8*)(ldsB + (size_t)(n * 8 + (s ^ (n & 7))) * 8);
      }
#pragma unroll
      for (int mt = 0; mt < 4; ++mt)
#pragma unroll
        for (int nt = 0; nt < 4; ++nt)
          acc[mt][nt] = __builtin_amdgcn_mfma_f32_16x16x32_bf16(
              af[mt], bfr[nt], acc[mt][nt], 0, 0, 0);
    }
    __syncthreads();
  }

#pragma unroll
  for (int nt = 0; nt < 4; ++nt) {
    int col = n0 + wn + nt * 16 + lr;
    if (col >= N) continue;
#pragma unroll
    for (int mt = 0; mt < 4; ++mt) {
      int row = m0 + wm + mt * 16 + lq * 4;
#pragma unroll
      for (int r = 0; r < 4; ++r) {
        float v = acc[mt][nt][r];
        if (headout) {
          size_t di = (col < 8) ? ((size_t)(rowoff + row + r) * 8 + col)
                                : ((size_t)Btot * 8 + rowoff + row + r);
          atomicAdd(Cf + di, v);
        } else {
          atomicAdd(Cf + (size_t)(row + r) * N + col, v);
        }
      }
    }
  }
}

// ---------------------------------------------------------------------------
// Fused prep: all weight transposes (fp32 [R,C] -> bf16 [C,R]), Wh build,
// pbuf zero, out bias init, x split/convert.  One launch, range ladder.
// ---------------------------------------------------------------------------
__device__ __forceinline__ void transpose_tile(
    const float* __restrict__ in, us* __restrict__ out,
    int R, int C, int bx, int by, float (*tile)[33])
{
  const int tx = threadIdx.x & 31, ty = threadIdx.x >> 5;
  const int c0 = bx * 32, r0 = by * 32;
#pragma unroll
  for (int i = 0; i < 4; ++i) {
    int r = r0 + ty + i * 8, c = c0 + tx;
    tile[ty + i * 8][tx] = (r < R && c < C) ? in[(size_t)r * C + c] : 0.f;
  }
  __syncthreads();
#pragma unroll
  for (int i = 0; i < 4; ++i) {
    int c = c0 + ty + i * 8, r = r0 + tx;
    if (c < C && r < R) out[(size_t)c * R + r] = f2bf(tile[tx][ty + i * 8]);
  }
}

__global__ __launch_bounds__(256)
void prep_kernel(const float* __restrict__ x,
                 const float* __restrict__ sW1, const float* __restrict__ sW2,
                 const float* __restrict__ sW3, const float* __restrict__ tW,
                 const float* __restrict__ rdW, const float* __restrict__ ruW,
                 const float* __restrict__ eW,
                 const float* __restrict__ aW, const float* __restrict__ cW,
                 const float* __restrict__ ab, const float* __restrict__ cb,
                 us* __restrict__ obs, us* __restrict__ task,
                 us* __restrict__ s1t, us* __restrict__ s2t,
                 us* __restrict__ s3t, us* __restrict__ tWt,
                 us* __restrict__ rdt, us* __restrict__ rut,
                 us* __restrict__ eWt, us* __restrict__ Wh,
                 float* __restrict__ pbuf, float* __restrict__ out)
{
  __shared__ float tile[32][33];
  int b = blockIdx.x;
  const int tid = threadIdx.x;

  if (b < 64)  { transpose_tile(sW1, s1t, 128, 512, b % 16, b / 16, tile); return; }
  b -= 64;
  if (b < 256) { transpose_tile(sW2, s2t, 512, 512, b % 16, b / 16, tile); return; }
  b -= 256;
  if (b < 512) { transpose_tile(sW3, s3t, 512, 1024, b % 32, b / 32, tile); return; }
  b -= 512;
  if (b < 64)  { transpose_tile(tW, tWt, 64, 1024, b % 32, b / 32, tile); return; }
  b -= 64;
  if (b < 128) { int l = b >> 6, r = b & 63;
                 transpose_tile(rdW + (size_t)l * 65536, rdt + (size_t)l * 65536,
                                1024, 64, r % 2, r / 2, tile); return; }
  b -= 128;
  if (b < 64)  { transpose_tile(ruW, rut, 64, 1024, b % 32, b / 32, tile); return; }
  b -= 64;
  if (b < 16384) { int l = b >> 10, r = b & 1023;
                 transpose_tile(eW + (size_t)l * 1048576, eWt + (size_t)l * 1048576,
                                1024, 1024, r % 32, r / 32, tile); return; }
  b -= 16384;
  if (b < 288) {  // Wh[o][e*1024+d] = aW[e][d][o] (o<8) | cW[e][d]
    int i = b * 256 + tid;
    int o = i / 8192, k = i - o * 8192;
    float v = (o < 8) ? aW[(size_t)k * 8 + o] : cW[k];
    Wh[i] = f2bf(v);
    return;
  }
  b -= 288;
  if (b < 4096) { pbuf[(size_t)b * 256 + tid] = 0.f; return; }
  b -= 4096;
  if (b < 288) {  // out bias init (overwritten by mix_head; kept, harmless)
    int i = b * 256 + tid;
    int bb = i / 9, o = i - bb * 9;
    float s = 0.f;
    if (o < 8) { for (int e = 0; e < 8; ++e) s += ab[e * 8 + o]; }
    else       { for (int e = 0; e < 8; ++e) s += cb[e]; }
    if (o < 8) out[(size_t)bb * 8 + o] = s;
    else       out[(size_t)8192 * 8 + bb] = s;
    return;
  }
  b -= 288;
  {  // split x(B,192) -> obs (B,128), task (B,64)
    int i = b * 256 + tid;
    int bb = i / 192, c = i - bb * 192;
    us v = f2bf(x[i]);
    if (c < 128) obs[(size_t)bb * 128 + c] = v;
    else         task[(size_t)bb * 64 + (c - 128)] = v;
  }
}

// pbuf[i] += rdb[i&63]; pbf[i] = bf16(pbuf[i])
__global__ __launch_bounds__(256)
void mk_pbf(float* __restrict__ pbuf, const float* __restrict__ rdb,
            us* __restrict__ pbf, int n)
{
  int i = blockIdx.x * 256 + threadIdx.x;
  if (i >= n) return;
  float v = pbuf[i] + rdb[i & 63];
  pbuf[i] = v;
  if (pbf) pbf[i] = f2bf(v);
}

// softmax over groups of 8; groups i >= biasFrom get +bias2[(i&7)*8+j] first
__global__ __launch_bounds__(256)
void softmax8_kernel(const float* __restrict__ p, float* __restrict__ probs,
                     const float* __restrict__ bias2, int biasFrom, int total)
{
  int i = blockIdx.x * 256 + threadIdx.x;
  if (i >= total) return;
  const float4 lo = *(const float4*)(p + (size_t)i * 8);
  const float4 hi = *(const float4*)(p + (size_t)i * 8 + 4);
  float v[8] = { lo.x, lo.y, lo.z, lo.w, hi.x, hi.y, hi.z, hi.w };
  if (i >= biasFrom) {
    const float* bb = bias2 + (i & 7) * 8;
#pragma unroll
    for (int j = 0; j < 8; ++j) v[j] += bb[j];
  }
  float m = v[0];
#pragma unroll
  for (int j = 1; j < 8; ++j) m = fmaxf(m, v[j]);
  float s = 0.f;
#pragma unroll
  for (int j = 0; j < 8; ++j) { v[j] = __expf(v[j] - m); s += v[j]; }
  float inv = 1.f / s;
  float4 olo = { v[0]*inv, v[1]*inv, v[2]*inv, v[3]*inv };
  float4 ohi = { v[4]*inv, v[5]*inv, v[6]*inv, v[7]*inv };
  *(float4*)(probs + (size_t)i * 8)     = olo;
  *(float4*)(probs + (size_t)i * 8 + 4) = ohi;
}

// out[i*sOutE + bl*sOutB + d] = sum_j P[bg,i,j]*he[j,bl,d]; block per local b
__global__ __launch_bounds__(256)
void mix_kernel(const us* __restrict__ he, const float* __restrict__ probs_l,
                us* __restrict__ xx, int b0, int chunkB,
                long long sOutE, long long sOutB)
{
  const int bl = blockIdx.x;
  const int bg = b0 + bl;
  __shared__ float P[64];
  if (threadIdx.x < 64) P[threadIdx.x] = probs_l[(size_t)bg * 64 + threadIdx.x];
  __syncthreads();
  const int t = threadIdx.x;
  const size_t es = (size_t)chunkB * 1024;
  const size_t rbase = (size_t)bl * 1024 + (size_t)t * 4;
  const size_t wbase = (size_t)bl * sOutB + (size_t)t * 4;
  float hv[8][4];
#pragma unroll
  for (int j = 0; j < 8; ++j) {
    ushort4 h4 = *(const ushort4*)(he + (size_t)j * es + rbase);
    hv[j][0] = bf2f(h4.x); hv[j][1] = bf2f(h4.y);
    hv[j][2] = bf2f(h4.z); hv[j][3] = bf2f(h4.w);
  }
#pragma unroll
  for (int i = 0; i < 8; ++i) {
    float o0 = 0.f, o1 = 0.f, o2 = 0.f, o3 = 0.f;
#pragma unroll
    for (int j = 0; j < 8; ++j) {
      float pij = P[i * 8 + j];
      o0 += pij * hv[j][0]; o1 += pij * hv[j][1];
      o2 += pij * hv[j][2]; o3 += pij * hv[j][3];
    }
    ushort4 ov = { f2bf(o0), f2bf(o1), f2bf(o2), f2bf(o3) };
    *(ushort4*)(xx + (size_t)i * sOutE + wbase) = ov;
  }
}

// ---------------------------------------------------------------------------
// mix_head: fused second mix + policy/value heads.  2 batch rows per block.
// Each thread covers d = t*4..t*4+3 for all 8 experts (32 k-elems of the
// 8192-long head reduction); the block covers the whole reduction for both
// rows.  Mix stays in fp32.  Wave shuffle-reduce + cross-wave LDS reduce.
// out: mu = out[bg*8+o] (o<8), values = out[Btot*8+bg].
// ---------------------------------------------------------------------------
__global__ __launch_bounds__(256)
void mix_head_kernel(const us* __restrict__ he, const float* __restrict__ probs_l,
                     const us* __restrict__ Wh, const float* __restrict__ ab,
                     const float* __restrict__ cb, float* __restrict__ out,
                     int b0, int chunkB, int Btot)
{
  const int r0 = blockIdx.x * 2;            // local row pair
  const int t = threadIdx.x;
  const int lane = t & 63;
  const int wave = t >> 6;
  __shared__ float P[2][64];
  __shared__ float red[2][9][4];
  if (t < 128)
    P[t >> 6][t & 63] = probs_l[(size_t)(b0 + r0 + (t >> 6)) * 64 + (t & 63)];
  __syncthreads();

  const size_t es = (size_t)chunkB * 1024;
  float xv[2][8][4];
#pragma unroll
  for (int r = 0; r < 2; ++r) {
#pragma unroll
    for (int i = 0; i < 8; ++i)
#pragma unroll
      for (int q = 0; q < 4; ++q) xv[r][i][q] = 0.f;
    const size_t rbase = (size_t)(r0 + r) * 1024 + (size_t)t * 4;
#pragma unroll
    for (int j = 0; j < 8; ++j) {
      ushort4 h4 = *(const ushort4*)(he + (size_t)j * es + rbase);
      float h0 = bf2f(h4.x), h1 = bf2f(h4.y), h2 = bf2f(h4.z), h3 = bf2f(h4.w);
#pragma unroll
      for (int i = 0; i < 8; ++i) {
        float p = P[r][i * 8 + j];
        xv[r][i][0] += p * h0; xv[r][i][1] += p * h1;
        xv[r][i][2] += p * h2; xv[r][i][3] += p * h3;
      }
    }
  }

  // head: s[r][o] = sum_{i,q} xv[r][i][q] * Wh[o][i*1024 + t*4 + q]
  float s[2][9];
#pragma unroll
  for (int o = 0; o < 9; ++o) { s[0][o] = 0.f; s[1][o] = 0.f; }
#pragma unroll
  for (int o = 0; o < 9; ++o) {
    const us* w = Wh + (size_t)o * 8192 + (size_t)t * 4;
#pragma unroll
    for (int i = 0; i < 8; ++i) {
      ushort4 w4 = *(const ushort4*)(w + i * 1024);
      float w0 = bf2f(w4.x), w1 = bf2f(w4.y), w2 = bf2f(w4.z), w3 = bf2f(w4.w);
      s[0][o] += xv[0][i][0]*w0 + xv[0][i][1]*w1 + xv[0][i][2]*w2 + xv[0][i][3]*w3;
      s[1][o] += xv[1][i][0]*w0 + xv[1][i][1]*w1 + xv[1][i][2]*w2 + xv[1][i][3]*w3;
    }
  }

  // wave shuffle-reduce (64-wide), then cross-wave via LDS
#pragma unroll
  for (int off = 32; off >= 1; off >>= 1) {
#pragma unroll
    for (int r = 0; r < 2; ++r)
#pragma unroll
      for (int o = 0; o < 9; ++o) s[r][o] += __shfl_down(s[r][o], off);
  }
  if (lane == 0) {
#pragma unroll
    for (int r = 0; r < 2; ++r)
#pragma unroll
      for (int o = 0; o < 9; ++o) red[r][o][wave] = s[r][o];
  }
  __syncthreads();
  if (t < 18) {
    int r = t / 9, o = t - r * 9;
    float v = red[r][o][0] + red[r][o][1] + red[r][o][2] + red[r][o][3];
    float bias = 0.f;
    if (o < 8) { for (int e = 0; e < 8; ++e) bias += ab[e * 8 + o]; }
    else       { for (int e = 0; e < 8; ++e) bias += cb[e]; }
    int bg = b0 + r0 + r;
    if (o < 8) out[(size_t)bg * 8 + o] = v + bias;
    else       out[(size_t)Btot * 8 + bg] = v + bias;
  }
}

// ---------------------------------------------------------------------------
extern "C" void kernel_launch(void* const* d_in, const int* in_sizes, int n_in,
                              void* d_out, int out_size, void* d_ws, size_t ws_size,
                              hipStream_t stream)
{
  const float* x   = (const float*)d_in[0];
  const float* sW1 = (const float*)d_in[1];
  const float* sb1 = (const float*)d_in[2];
  const float* sW2 = (const float*)d_in[3];
  const float* sb2 = (const float*)d_in[4];
  const float* sW3 = (const float*)d_in[5];
  const float* sb3 = (const float*)d_in[6];
  const float* tW  = (const float*)d_in[7];
  const float* tb  = (const float*)d_in[8];
  const float* rdW = (const float*)d_in[9];
  const float* rdb = (const float*)d_in[10];
  const float* ruW = (const float*)d_in[11];
  const float* rub = (const float*)d_in[12];
  const float* eW  = (const float*)d_in[13];
  const float* eb  = (const float*)d_in[14];
  const float* aW  = (const float*)d_in[15];
  const float* ab  = (const float*)d_in[16];
  const float* cW  = (const float*)d_in[17];
  const float* cb  = (const float*)d_in[18];
  float* out = (float*)d_out;

  const int B = 8192;
  const size_t BD = (size_t)B * 1024;
  char* ws = (char*)d_ws;

  // ---- arena: persistent region -------------------------------------------
  size_t o = 0;
  auto take = [&](size_t bytes) { size_t r = o; o = (o + bytes + 255) & ~(size_t)255; return r; };
  const size_t off_s1t  = take((size_t)512 * 128 * 2);
  const size_t off_s2t  = take((size_t)512 * 512 * 2);
  const size_t off_s3t  = take((size_t)1024 * 512 * 2);
  const size_t off_tWt  = take((size_t)1024 * 64 * 2);
  const size_t off_rdt  = take((size_t)2 * 64 * 1024 * 2);
  const size_t off_rut  = take((size_t)1024 * 64 * 2);
  const size_t off_eWt  = take((size_t)16 * 1024 * 1024 * 2);
  const size_t off_fobs = take(BD * 2);
  const size_t off_probs= take((size_t)2 * B * 64 * 4);
  const size_t off_Wh   = take((size_t)9 * 8192 * 2);
  const size_t P0 = o;
  // ---- scratch overlays (routing phase) -----------------------------------
  const size_t off_rin  = P0;                 // also h1
  const size_t off_rbuf = off_rin + BD * 2;   // also h2, u
  const size_t off_pbuf = off_rbuf + BD * 2;
  const size_t off_pbf  = off_pbuf + (size_t)2 * B * 64 * 4;
  const size_t off_obs  = off_pbf + (size_t)B * 64 * 2;
  const size_t off_task = off_obs + (size_t)B * 128 * 2;
  const size_t routing_end = off_task + (size_t)B * 64 * 2;

  // ---- expert-stage chunk selection (he/xx overlay scratch at P0) ---------
  int chunk = 0;
  const int cands[4] = {8192, 4096, 2048, 1024};
  for (int i = 0; i < 4; ++i) {
    size_t need = P0 + (size_t)cands[i] * 32768;  // he + xx
    if (need <= ws_size) { chunk = cands[i]; break; }
  }
  if (!chunk || routing_end > ws_size) return;

  us* s1t  = (us*)(ws + off_s1t);
  us* s2t  = (us*)(ws + off_s2t);
  us* s3t  = (us*)(ws + off_s3t);
  us* tWt  = (us*)(ws + off_tWt);
  us* rdt  = (us*)(ws + off_rdt);
  us* rut  = (us*)(ws + off_rut);
  us* eWt  = (us*)(ws + off_eWt);
  us* fobs = (us*)(ws + off_fobs);
  float* probs = (float*)(ws + off_probs);
  us* Wh   = (us*)(ws + off_Wh);
  us* rin  = (us*)(ws + off_rin);
  us* rbuf = (us*)(ws + off_rbuf);
  float* pbuf = (float*)(ws + off_pbuf);
  us* pbf  = (us*)(ws + off_pbf);
  us* obs_bf  = (us*)(ws + off_obs);
  us* task_bf = (us*)(ws + off_task);
  us* h1 = rin;
  us* h2 = rbuf;
  us* he = (us*)(ws + P0);
  us* xx = (us*)(ws + P0 + (size_t)chunk * 16384);

  // ---- fused prep: transposes + Wh + pbuf zero + out bias + x split -------
  prep_kernel<<<dim3(28288), 256, 0, stream>>>(x, sW1, sW2, sW3, tW, rdW, ruW,
      eW, aW, cW, ab, cb, obs_bf, task_bf, s1t, s2t, s3t, tWt, rdt, rut,
      eWt, Wh, pbuf, out);

  // ---- shared MLP ---------------------------------------------------------
  gemm_main<true, true, false, false, false><<<dim3(4, 64, 1), 256, 0, stream>>>(
      obs_bf, s1t, sb1, h1, (us*)0, (const us*)0, 512, 128, 128, 128, 0, 0, 0, 0);
  gemm_main<true, true, false, false, false><<<dim3(4, 64, 1), 256, 0, stream>>>(
      h1, s2t, sb2, h2, (us*)0, (const us*)0, 512, 512, 512, 512, 0, 0, 0, 0);
  gemm_main<true, false, false, false, false><<<dim3(8, 64, 1), 256, 0, stream>>>(
      h2, s3t, sb3, fobs, (us*)0, (const us*)0, 1024, 512, 512, 512, 0, 0, 0, 0);
  // z-GEMM fused: rin = relu(task@tW+tb)*fobs ; rbuf = relu(rin)
  gemm_main<true, true, true, false, true><<<dim3(8, 64, 1), 256, 0, stream>>>(
      task_bf, tWt, tb, rin, rbuf, fobs, 1024, 64, 64, 64, 0, 0, 0, 0);

  // ---- routing (layers 0,1; layer 2 is dead code) -------------------------
  gemm_splitk<<<dim3(1, 64, 4), 256, 0, stream>>>(rbuf, rdt, pbuf,
      64, 256, 1024, 1024, 256, 256, 0, 0, 0);                       // p0
  mk_pbf<<<dim3((B * 64 + 255) / 256), 256, 0, stream>>>(pbuf, rdb, pbf, B * 64);
  // u-GEMM fused: rbuf = relu((pbf@ruW+rub) * rin)
  gemm_main<true, false, true, true, false><<<dim3(8, 64, 1), 256, 0, stream>>>(
      pbf, rut, rub, rbuf, (us*)0, rin, 1024, 64, 64, 64, 0, 0, 0, 0);
  gemm_splitk<<<dim3(1, 64, 4), 256, 0, stream>>>(rbuf, rdt + 65536,
      pbuf + (size_t)B * 64, 64, 256, 1024, 1024, 256, 256, 0, 0, 0); // p1
  softmax8_kernel<<<dim3((2 * B * 8 + 255) / 256), 256, 0, stream>>>(
      pbuf, probs, rdb + 64, B * 8, 2 * B * 8);

  // ---- expert stage, chunked over batch -----------------------------------
  // expert GEMMs on gemm_k64 (chunk%256==0 always; K=1024 -> NT=16)
  const long long sHE = (long long)chunk * 1024;
  for (int b0 = 0; b0 < B; b0 += chunk) {
    gemm_k64<true, true><<<dim3(4, chunk / 256, 8), 512, 0, stream>>>(
        fobs + (size_t)b0 * 1024, eWt, eb, he,
        1024, 1024, 1024, 1024, 0, 1048576, 1024, sHE);
    mix_kernel<<<dim3(chunk), 256, 0, stream>>>(he, probs, xx, b0, chunk, sHE, 1024);
    gemm_k64<true, true><<<dim3(4, chunk / 256, 8), 512, 0, stream>>>(
        xx, eWt + (size_t)8 * 1048576, eb + 8192, he,
        1024, 1024, 1024, 1024, sHE, 1048576, 1024, sHE);
    // fused second mix + heads: no xx b-major materialization, no atomics
    mix_head_kernel<<<dim3(chunk / 2), 256, 0, stream>>>(
        he, probs + (size_t)B * 64, Wh, ab, cb, out, b0, chunk, B);
  }
}